// Round 13
// baseline (36.471 us; speedup 1.0000x reference)
//
#include <hip/hip_runtime.h>

#define H 128
#define N 1024

static __device__ __forceinline__ float rdlane(float v, int l) {
    return __int_as_float(__builtin_amdgcn_readlane(__float_as_int(v), l));
}

// ---------------------------------------------------------------------------
// prep: byte-identical to the 25.5 us winner.
//   Lp[i][h] = w2[h]*(L[i][h] + b1[h]);  Rt[h][j] = w2[h]*R[j][h];
//   c[j] = 0.5 * sum_h Rt[h][j].
// ---------------------------------------------------------------------------
__global__ __launch_bounds__(512) void prep_kernel(
    const float* __restrict__ x, const float* __restrict__ W1,
    const float* __restrict__ b1, const float* __restrict__ W2,
    float* __restrict__ Lp, float* __restrict__ Rt, float* __restrict__ c)
{
    constexpr int PF = 8;
    __shared__ float e_s[4][H];
    __shared__ float cred[4][2];
    const int t = threadIdx.x;
    const int i0 = blockIdx.x * 4;

    if (t < 256) {                       // normalize: wave w owns row w
        const int row = t >> 6, lane = t & 63;
        const float2 v = *reinterpret_cast<const float2*>(&x[(i0 + row) * H + 2 * lane]);
        float s = v.x * v.x + v.y * v.y;
#pragma unroll
        for (int off = 32; off; off >>= 1) s += __shfl_xor(s, off);
        const float rn = 1.0f / fmaxf(sqrtf(s), 1e-12f);
        e_s[row][2 * lane]     = v.x * rn;
        e_s[row][2 * lane + 1] = v.y * rn;
    }
    __syncthreads();

    const int h = t & (H - 1);
    const int q = t >> 7;                // 0,1 -> L ; 2,3 -> R
    const int r0 = (q & 1) * 2;          // row pair {0,1} or {2,3}
    const float* Wb = W1 + (q >= 2 ? H * H : 0) + h;

    float acc0 = 0.f, acc1 = 0.f;
    float wbuf[PF];
#pragma unroll
    for (int p = 0; p < PF; ++p) wbuf[p] = Wb[p * H];

    for (int kb = 0; kb < H - PF; kb += PF) {
#pragma unroll
        for (int p = 0; p < PF; ++p) {
            const float w = wbuf[p];
            wbuf[p] = Wb[(kb + p + PF) * H];
            acc0 = fmaf(e_s[r0][kb + p],     w, acc0);
            acc1 = fmaf(e_s[r0 + 1][kb + p], w, acc1);
        }
    }
#pragma unroll
    for (int p = 0; p < PF; ++p) {
        const int k = H - PF + p;
        acc0 = fmaf(e_s[r0][k],     wbuf[p], acc0);
        acc1 = fmaf(e_s[r0 + 1][k], wbuf[p], acc1);
    }

    const float w2h = W2[h];
    if (q < 2) {
        const float bb = b1[h];
        Lp[(i0 + r0) * H + h]     = w2h * (acc0 + bb);
        Lp[(i0 + r0 + 1) * H + h] = w2h * (acc1 + bb);
    } else {
        const float v0 = w2h * acc0, v1 = w2h * acc1;
        Rt[h * N + (i0 + r0)]     = v0;
        Rt[h * N + (i0 + r0 + 1)] = v1;
        float s0 = v0, s1 = v1;          // c_j partial sums over h
#pragma unroll
        for (int off = 32; off; off >>= 1) {
            s0 += __shfl_xor(s0, off);
            s1 += __shfl_xor(s1, off);
        }
        const int wv = t >> 6;           // 4..7
        if ((t & 63) == 0) { cred[wv - 4][0] = s0; cred[wv - 4][1] = s1; }
    }
    __syncthreads();
    if (t < 4) {
        const int r = t;
        c[i0 + r] = 0.5f * (cred[(r >> 1) * 2][r & 1] + cred[(r >> 1) * 2 + 1][r & 1]);
    }
}

// ---------------------------------------------------------------------------
// adj: winner skeleton, SINGLE DELTA — zero in-loop LDS.
//   A (4 rows x 128 h, wave-uniform) packed across lanes: lane l holds
//   aA0[r]=Lp[r][l], aA1[r]=Lp[r][64+l]; sgn likewise in sg0/sg1.
//   Per h-step (h uniform): 5x v_readlane (4 A rows + sgn -> SGPRs) +
//   8 v_add + 8 v_fma(|.|) ; 1 coalesced float2 VMEM (PF=8 rotating).
//   Two 64-step sections keep register indices compile-time.
// ---------------------------------------------------------------------------
__global__ __launch_bounds__(512) void adj_kernel(
    const float* __restrict__ Lp, const float* __restrict__ Rt,
    const float* __restrict__ W2, const float* __restrict__ c,
    float* __restrict__ out)
{
    constexpr int II = 4, PF = 8;
    __shared__ float red_m[II][8];
    __shared__ float red_s[II][8];

    const int t = threadIdx.x;
    const int lane = t & 63, wave = t >> 6;
    const int i0 = blockIdx.x * II;
    const int j0 = t * 2;

    // ---- A-pack + sign-pack into registers (lane-distributed) ----
    float aA0[II], aA1[II];
#pragma unroll
    for (int r = 0; r < II; ++r) {
        aA0[r] = Lp[(i0 + r) * H + lane];
        aA1[r] = Lp[(i0 + r) * H + 64 + lane];
    }
    const float sg0 = (W2[lane]      >= 0.f) ? 0.5f : -0.5f;
    const float sg1 = (W2[64 + lane] >= 0.f) ? 0.5f : -0.5f;

    const float2 cj = *reinterpret_cast<const float2*>(&c[j0]);

    float accx[II], accy[II];
#pragma unroll
    for (int ii = 0; ii < II; ++ii) { accx[ii] = cj.x; accy[ii] = cj.y; }

    float2 rbuf[PF];
#pragma unroll
    for (int p = 0; p < PF; ++p)
        rbuf[p] = *reinterpret_cast<const float2*>(&Rt[p * N + j0]);

#define STEP(H_, LI_, A_, SG_, DO_PF_)                                        \
    {                                                                         \
        const float2 r_ = rbuf[(H_) & 7];                                     \
        if (DO_PF_)                                                           \
            rbuf[(H_) & 7] =                                                  \
                *reinterpret_cast<const float2*>(&Rt[((H_) + PF) * N + j0]);  \
        const float s_ = rdlane(SG_, (LI_));                                  \
        float a_[II];                                                         \
        _Pragma("unroll")                                                     \
        for (int r = 0; r < II; ++r) a_[r] = rdlane(A_[r], (LI_));            \
        _Pragma("unroll")                                                     \
        for (int ii = 0; ii < II; ++ii) {                                     \
            accx[ii] = fmaf(s_, fabsf(a_[ii] + r_.x), accx[ii]);              \
            accy[ii] = fmaf(s_, fabsf(a_[ii] + r_.y), accy[ii]);              \
        }                                                                     \
    }

    // section k=0: h in [0,64), all groups prefetch (reaches row 71 max)
    for (int hb = 0; hb < 64; hb += PF) {
#pragma unroll
        for (int p = 0; p < PF; ++p) STEP(hb + p, hb + p, aA0, sg0, true)
    }
    // section k=1: h in [64,120), prefetch reaches row 127 exactly
    for (int hb = 64; hb < H - PF; hb += PF) {
#pragma unroll
        for (int p = 0; p < PF; ++p) STEP(hb + p, hb + p - 64, aA1, sg1, true)
    }
    // tail: h = 120..127, no prefetch
#pragma unroll
    for (int p = 0; p < PF; ++p) STEP(H - PF + p, H - PF + p - 64, aA1, sg1, false)
#undef STEP

    // ---- softmax over j (block = full row) ----
#pragma unroll
    for (int ii = 0; ii < II; ++ii) {
        float m = fmaxf(accx[ii], accy[ii]);
#pragma unroll
        for (int off = 32; off; off >>= 1) m = fmaxf(m, __shfl_xor(m, off));
        if (lane == 0) red_m[ii][wave] = m;
    }
    __syncthreads();

    float mm[II];
#pragma unroll
    for (int ii = 0; ii < II; ++ii) {
        float m = red_m[ii][0];
#pragma unroll
        for (int w = 1; w < 8; ++w) m = fmaxf(m, red_m[ii][w]);
        mm[ii] = m;
    }

#pragma unroll
    for (int ii = 0; ii < II; ++ii) {
        accx[ii] = expf(accx[ii] - mm[ii]);
        accy[ii] = expf(accy[ii] - mm[ii]);
        float s = accx[ii] + accy[ii];
#pragma unroll
        for (int off = 32; off; off >>= 1) s += __shfl_xor(s, off);
        if (lane == 0) red_s[ii][wave] = s;
    }
    __syncthreads();

#pragma unroll
    for (int ii = 0; ii < II; ++ii) {
        float s = red_s[ii][0];
#pragma unroll
        for (int w = 1; w < 8; ++w) s += red_s[ii][w];
        const float r = 1.0f / s;
        float2 o;
        o.x = accx[ii] * r;
        o.y = accy[ii] * r;
        *reinterpret_cast<float2*>(&out[(i0 + ii) * N + j0]) = o;
    }
}

extern "C" void kernel_launch(void* const* d_in, const int* in_sizes, int n_in,
                              void* d_out, int out_size, void* d_ws, size_t ws_size,
                              hipStream_t stream) {
    const float* x  = (const float*)d_in[0];   // (N,H)
    const float* W1 = (const float*)d_in[1];   // (2H,H)
    const float* b1 = (const float*)d_in[2];   // (H,)
    const float* W2 = (const float*)d_in[3];   // (H,1)
    // d_in[4] = b2 — cancels under softmax, not needed.
    float* out = (float*)d_out;

    float* Lp = (float*)d_ws;        // N*H
    float* Rt = Lp + N * H;          // H*N (transposed, w2-scaled)
    float* cc = Rt + H * N;          // N

    prep_kernel<<<N / 4, 512, 0, stream>>>(x, W1, b1, W2, Lp, Rt, cc);
    adj_kernel<<<N / 4, 512, 0, stream>>>(Lp, Rt, W2, cc, out);
}

// Round 14
// 30.063 us; speedup vs baseline: 1.2132x; 1.2132x over previous
//
#include <hip/hip_runtime.h>

#define H 128
#define N 1024

// ---------------------------------------------------------------------------
// prep: byte-identical to the 25.5 us winner.
//   Lp[i][h] = w2[h]*(L[i][h] + b1[h]);  Rt[h][j] = w2[h]*R[j][h];
//   c[j] = 0.5 * sum_h Rt[h][j].
// ---------------------------------------------------------------------------
__global__ __launch_bounds__(512) void prep_kernel(
    const float* __restrict__ x, const float* __restrict__ W1,
    const float* __restrict__ b1, const float* __restrict__ W2,
    float* __restrict__ Lp, float* __restrict__ Rt, float* __restrict__ c)
{
    constexpr int PF = 8;
    __shared__ float e_s[4][H];
    __shared__ float cred[4][2];
    const int t = threadIdx.x;
    const int i0 = blockIdx.x * 4;

    if (t < 256) {                       // normalize: wave w owns row w
        const int row = t >> 6, lane = t & 63;
        const float2 v = *reinterpret_cast<const float2*>(&x[(i0 + row) * H + 2 * lane]);
        float s = v.x * v.x + v.y * v.y;
#pragma unroll
        for (int off = 32; off; off >>= 1) s += __shfl_xor(s, off);
        const float rn = 1.0f / fmaxf(sqrtf(s), 1e-12f);
        e_s[row][2 * lane]     = v.x * rn;
        e_s[row][2 * lane + 1] = v.y * rn;
    }
    __syncthreads();

    const int h = t & (H - 1);
    const int q = t >> 7;                // 0,1 -> L ; 2,3 -> R
    const int r0 = (q & 1) * 2;          // row pair {0,1} or {2,3}
    const float* Wb = W1 + (q >= 2 ? H * H : 0) + h;

    float acc0 = 0.f, acc1 = 0.f;
    float wbuf[PF];
#pragma unroll
    for (int p = 0; p < PF; ++p) wbuf[p] = Wb[p * H];

    for (int kb = 0; kb < H - PF; kb += PF) {
#pragma unroll
        for (int p = 0; p < PF; ++p) {
            const float w = wbuf[p];
            wbuf[p] = Wb[(kb + p + PF) * H];
            acc0 = fmaf(e_s[r0][kb + p],     w, acc0);
            acc1 = fmaf(e_s[r0 + 1][kb + p], w, acc1);
        }
    }
#pragma unroll
    for (int p = 0; p < PF; ++p) {
        const int k = H - PF + p;
        acc0 = fmaf(e_s[r0][k],     wbuf[p], acc0);
        acc1 = fmaf(e_s[r0 + 1][k], wbuf[p], acc1);
    }

    const float w2h = W2[h];
    if (q < 2) {
        const float bb = b1[h];
        Lp[(i0 + r0) * H + h]     = w2h * (acc0 + bb);
        Lp[(i0 + r0 + 1) * H + h] = w2h * (acc1 + bb);
    } else {
        const float v0 = w2h * acc0, v1 = w2h * acc1;
        Rt[h * N + (i0 + r0)]     = v0;
        Rt[h * N + (i0 + r0 + 1)] = v1;
        float s0 = v0, s1 = v1;          // c_j partial sums over h
#pragma unroll
        for (int off = 32; off; off >>= 1) {
            s0 += __shfl_xor(s0, off);
            s1 += __shfl_xor(s1, off);
        }
        const int wv = t >> 6;           // 4..7
        if ((t & 63) == 0) { cred[wv - 4][0] = s0; cred[wv - 4][1] = s1; }
    }
    __syncthreads();
    if (t < 4) {
        const int r = t;
        c[i0 + r] = 0.5f * (cred[(r >> 1) * 2][r & 1] + cred[(r >> 1) * 2 + 1][r & 1]);
    }
}

// ---------------------------------------------------------------------------
// adj (partial): grid 256 = 64 i-blocks x 4 j-slices; js = bid&3 so the
//   j-slice is XCD-affine under round-robin dispatch. Block = 16 rows x
//   256 cols, 512 threads: row-group tg = t>>7 owns rows r0..r0+3; thread
//   covers cols j0 = jbase + 2*(t&127). Per-thread inner loop is BYTE-
//   IDENTICAL to the 25.5 us winner (b128 LsT bcast + b32 sgn bcast +
//   PF=8 float2 Rt stream + 16 VALU). Rt read/block = 128 KB (slice only):
//   total Rt traffic 32 MB (4x less) and slice-local per XCD pair.
//   Writes unnormalized p = exp(l - m_blk) to out + (m,s) per (row,slice).
// ---------------------------------------------------------------------------
__global__ __launch_bounds__(512) void adj_kernel(
    const float* __restrict__ Lp, const float* __restrict__ Rt,
    const float* __restrict__ W2, const float* __restrict__ c,
    float* __restrict__ out, float* __restrict__ m_arr,
    float* __restrict__ s_arr)
{
    constexpr int II = 4, PF = 8;
    __shared__ float LsT[H][16];
    __shared__ float sgn[H];
    __shared__ float red_m[16][2];
    __shared__ float red_s[16][2];

    const int t = threadIdx.x;
    const int lane = t & 63, wave = t >> 6;
    const int bid = blockIdx.x;
    const int js = bid & 3;
    const int ib = bid >> 2;
    const int i0 = ib * 16;
    const int jbase = js * 256;
    const int tg = t >> 7;               // row group 0..3
    const int r0 = i0 + tg * 4;
    const int j0 = jbase + (t & 127) * 2;

    {   // stage LsT (16 rows x 128 h) and sgn
        const int h = t & 127;
        float4 lv;
        lv.x = Lp[(i0 + 4 * tg + 0) * H + h];
        lv.y = Lp[(i0 + 4 * tg + 1) * H + h];
        lv.z = Lp[(i0 + 4 * tg + 2) * H + h];
        lv.w = Lp[(i0 + 4 * tg + 3) * H + h];
        *reinterpret_cast<float4*>(&LsT[h][4 * tg]) = lv;
        if (t < H) sgn[t] = (W2[t] >= 0.f) ? 0.5f : -0.5f;
    }
    const float2 cj = *reinterpret_cast<const float2*>(&c[j0]);
    __syncthreads();

    float accx[II], accy[II];
#pragma unroll
    for (int ii = 0; ii < II; ++ii) { accx[ii] = cj.x; accy[ii] = cj.y; }

    float2 rbuf[PF];
#pragma unroll
    for (int p = 0; p < PF; ++p)
        rbuf[p] = *reinterpret_cast<const float2*>(&Rt[p * N + j0]);

    for (int hb = 0; hb < H - PF; hb += PF) {
#pragma unroll
        for (int p = 0; p < PF; ++p) {
            const int h = hb + p;
            const float2 r = rbuf[p];
            rbuf[p] = *reinterpret_cast<const float2*>(&Rt[(h + PF) * N + j0]);
            const float4 lv = *reinterpret_cast<const float4*>(&LsT[h][4 * tg]);
            const float s = sgn[h];
            const float* lp = &lv.x;
#pragma unroll
            for (int ii = 0; ii < II; ++ii) {
                accx[ii] = fmaf(s, fabsf(lp[ii] + r.x), accx[ii]);
                accy[ii] = fmaf(s, fabsf(lp[ii] + r.y), accy[ii]);
            }
        }
    }
#pragma unroll
    for (int p = 0; p < PF; ++p) {       // tail, no prefetch
        const int h = H - PF + p;
        const float2 r = rbuf[p];
        const float4 lv = *reinterpret_cast<const float4*>(&LsT[h][4 * tg]);
        const float s = sgn[h];
        const float* lp = &lv.x;
#pragma unroll
        for (int ii = 0; ii < II; ++ii) {
            accx[ii] = fmaf(s, fabsf(lp[ii] + r.x), accx[ii]);
            accy[ii] = fmaf(s, fabsf(lp[ii] + r.y), accy[ii]);
        }
    }

    // ---- per-(row,slice) max over the 128 threads of the row group ----
#pragma unroll
    for (int ii = 0; ii < II; ++ii) {
        float m = fmaxf(accx[ii], accy[ii]);
#pragma unroll
        for (int off = 32; off; off >>= 1) m = fmaxf(m, __shfl_xor(m, off));
        if (lane == 0) red_m[4 * tg + ii][wave & 1] = m;
    }
    __syncthreads();

    float mm[II];
#pragma unroll
    for (int ii = 0; ii < II; ++ii)
        mm[ii] = fmaxf(red_m[4 * tg + ii][0], red_m[4 * tg + ii][1]);

    // ---- exp + per-(row,slice) sum; write unnormalized p ----
#pragma unroll
    for (int ii = 0; ii < II; ++ii) {
        accx[ii] = expf(accx[ii] - mm[ii]);
        accy[ii] = expf(accy[ii] - mm[ii]);
        float s = accx[ii] + accy[ii];
#pragma unroll
        for (int off = 32; off; off >>= 1) s += __shfl_xor(s, off);
        if (lane == 0) red_s[4 * tg + ii][wave & 1] = s;
        float2 o; o.x = accx[ii]; o.y = accy[ii];
        *reinterpret_cast<float2*>(&out[(r0 + ii) * N + j0]) = o;
    }
    __syncthreads();

    if ((t & 127) == 0) {                // one thread per row group
#pragma unroll
        for (int ii = 0; ii < II; ++ii) {
            m_arr[(r0 + ii) * 4 + js] = mm[ii];
            s_arr[(r0 + ii) * 4 + js] = red_s[4 * tg + ii][0] + red_s[4 * tg + ii][1];
        }
    }
}

// ---------------------------------------------------------------------------
// combine: grid N/4 = 256 blocks x 256 threads. Per row: M = max_js m,
//   S = sum_js exp(m-M)*s; out[i][j] *= exp(m_js - M)/S  (js = j>>8).
// ---------------------------------------------------------------------------
__global__ __launch_bounds__(256) void comb_kernel(
    float* __restrict__ out, const float* __restrict__ m_arr,
    const float* __restrict__ s_arr)
{
    __shared__ float fs[4][4];
    const int t = threadIdx.x;
    const int i0 = blockIdx.x * 4;

    if (t < 16) {
        const int rr = t >> 2, js = t & 3;
        const int i = i0 + rr;
        const float m0 = m_arr[i * 4 + 0], m1 = m_arr[i * 4 + 1];
        const float m2 = m_arr[i * 4 + 2], m3 = m_arr[i * 4 + 3];
        const float M = fmaxf(fmaxf(m0, m1), fmaxf(m2, m3));
        const float S = expf(m0 - M) * s_arr[i * 4 + 0]
                      + expf(m1 - M) * s_arr[i * 4 + 1]
                      + expf(m2 - M) * s_arr[i * 4 + 2]
                      + expf(m3 - M) * s_arr[i * 4 + 3];
        const float mj = (js == 0) ? m0 : (js == 1) ? m1 : (js == 2) ? m2 : m3;
        fs[rr][js] = expf(mj - M) / S;
    }
    __syncthreads();

    const int jsl = t >> 6;              // slice of this thread's float4
#pragma unroll
    for (int rr = 0; rr < 4; ++rr) {
        float4 v = *reinterpret_cast<const float4*>(&out[(i0 + rr) * N + 4 * t]);
        const float f = fs[rr][jsl];
        v.x *= f; v.y *= f; v.z *= f; v.w *= f;
        *reinterpret_cast<float4*>(&out[(i0 + rr) * N + 4 * t]) = v;
    }
}

extern "C" void kernel_launch(void* const* d_in, const int* in_sizes, int n_in,
                              void* d_out, int out_size, void* d_ws, size_t ws_size,
                              hipStream_t stream) {
    const float* x  = (const float*)d_in[0];   // (N,H)
    const float* W1 = (const float*)d_in[1];   // (2H,H)
    const float* b1 = (const float*)d_in[2];   // (H,)
    const float* W2 = (const float*)d_in[3];   // (H,1)
    // d_in[4] = b2 — cancels under softmax, not needed.
    float* out = (float*)d_out;

    float* Lp = (float*)d_ws;            // N*H
    float* Rt = Lp + N * H;              // H*N (transposed, w2-scaled)
    float* cc = Rt + H * N;              // N
    float* m_arr = cc + N;               // N*4
    float* s_arr = m_arr + 4 * N;        // N*4

    prep_kernel<<<N / 4, 512, 0, stream>>>(x, W1, b1, W2, Lp, Rt, cc);
    adj_kernel<<<256, 512, 0, stream>>>(Lp, Rt, W2, cc, out, m_arr, s_arr);
    comb_kernel<<<N / 4, 256, 0, stream>>>(out, m_arr, s_arr);
}

// Round 15
// 26.797 us; speedup vs baseline: 1.3610x; 1.1219x over previous
//
#include <hip/hip_runtime.h>

#define H 128
#define N 1024

// ---------------------------------------------------------------------------
// prep: byte-identical to the 25.5 us winner.
//   Lp[i][h] = w2[h]*(L[i][h] + b1[h]);  Rt[h][j] = w2[h]*R[j][h];
//   c[j] = 0.5 * sum_h Rt[h][j].
// ---------------------------------------------------------------------------
__global__ __launch_bounds__(512) void prep_kernel(
    const float* __restrict__ x, const float* __restrict__ W1,
    const float* __restrict__ b1, const float* __restrict__ W2,
    float* __restrict__ Lp, float* __restrict__ Rt, float* __restrict__ c)
{
    constexpr int PF = 8;
    __shared__ float e_s[4][H];
    __shared__ float cred[4][2];
    const int t = threadIdx.x;
    const int i0 = blockIdx.x * 4;

    if (t < 256) {                       // normalize: wave w owns row w
        const int row = t >> 6, lane = t & 63;
        const float2 v = *reinterpret_cast<const float2*>(&x[(i0 + row) * H + 2 * lane]);
        float s = v.x * v.x + v.y * v.y;
#pragma unroll
        for (int off = 32; off; off >>= 1) s += __shfl_xor(s, off);
        const float rn = 1.0f / fmaxf(sqrtf(s), 1e-12f);
        e_s[row][2 * lane]     = v.x * rn;
        e_s[row][2 * lane + 1] = v.y * rn;
    }
    __syncthreads();

    const int h = t & (H - 1);
    const int q = t >> 7;                // 0,1 -> L ; 2,3 -> R
    const int r0 = (q & 1) * 2;          // row pair {0,1} or {2,3}
    const float* Wb = W1 + (q >= 2 ? H * H : 0) + h;

    float acc0 = 0.f, acc1 = 0.f;
    float wbuf[PF];
#pragma unroll
    for (int p = 0; p < PF; ++p) wbuf[p] = Wb[p * H];

    for (int kb = 0; kb < H - PF; kb += PF) {
#pragma unroll
        for (int p = 0; p < PF; ++p) {
            const float w = wbuf[p];
            wbuf[p] = Wb[(kb + p + PF) * H];
            acc0 = fmaf(e_s[r0][kb + p],     w, acc0);
            acc1 = fmaf(e_s[r0 + 1][kb + p], w, acc1);
        }
    }
#pragma unroll
    for (int p = 0; p < PF; ++p) {
        const int k = H - PF + p;
        acc0 = fmaf(e_s[r0][k],     wbuf[p], acc0);
        acc1 = fmaf(e_s[r0 + 1][k], wbuf[p], acc1);
    }

    const float w2h = W2[h];
    if (q < 2) {
        const float bb = b1[h];
        Lp[(i0 + r0) * H + h]     = w2h * (acc0 + bb);
        Lp[(i0 + r0 + 1) * H + h] = w2h * (acc1 + bb);
    } else {
        const float v0 = w2h * acc0, v1 = w2h * acc1;
        Rt[h * N + (i0 + r0)]     = v0;
        Rt[h * N + (i0 + r0 + 1)] = v1;
        float s0 = v0, s1 = v1;          // c_j partial sums over h
#pragma unroll
        for (int off = 32; off; off >>= 1) {
            s0 += __shfl_xor(s0, off);
            s1 += __shfl_xor(s1, off);
        }
        const int wv = t >> 6;           // 4..7
        if ((t & 63) == 0) { cred[wv - 4][0] = s0; cred[wv - 4][1] = s1; }
    }
    __syncthreads();
    if (t < 4) {
        const int r = t;
        c[i0 + r] = 0.5f * (cred[(r >> 1) * 2][r & 1] + cred[(r >> 1) * 2 + 1][r & 1]);
    }
}

// ---------------------------------------------------------------------------
// adj: grid N/4 = 256 blocks x 256 threads (1 wave/SIMD).
//   thread t: rows i0..i0+3 (II=4), cols j0 = 4t..4t+3 (JJ=4).
//   Resolves the R2/R3 confound: R2's JJ=4 shape but with R3's PF=8 depth
//   AND the 2-op abs identity (R2 ran 3-op relu + extra w2 LDS read).
//   Per h-step per wave: 1 float4 VMEM (1KB, full coalescing) + 1 b128 +
//   1 b32 LDS broadcast + 32 VALU -> half the mem instrs/element vs winner.
//   logit'[i][j] = c[j] + sum_h s_h*|Lp[i][h] + Rt[h][j]|, s_h = ±0.5.
// ---------------------------------------------------------------------------
__global__ __launch_bounds__(256) void adj_kernel(
    const float* __restrict__ Lp, const float* __restrict__ Rt,
    const float* __restrict__ W2, const float* __restrict__ c,
    float* __restrict__ out)
{
    constexpr int II = 4, JJ = 4, PF = 8;
    __shared__ float LsT[H][4];
    __shared__ float sgn[H];
    __shared__ float red_m[II][4];
    __shared__ float red_s[II][4];

    const int t = threadIdx.x;
    const int lane = t & 63, wave = t >> 6;
    const int i0 = blockIdx.x * II;
    const int j0 = t * JJ;

    if (t < H) {
        sgn[t] = (W2[t] >= 0.f) ? 0.5f : -0.5f;
        float4 lv;
        lv.x = Lp[(i0 + 0) * H + t];
        lv.y = Lp[(i0 + 1) * H + t];
        lv.z = Lp[(i0 + 2) * H + t];
        lv.w = Lp[(i0 + 3) * H + t];
        *reinterpret_cast<float4*>(&LsT[t][0]) = lv;
    }
    const float4 cj = *reinterpret_cast<const float4*>(&c[j0]);
    __syncthreads();

    float acc[II][JJ];
    const float* cjp = &cj.x;
#pragma unroll
    for (int ii = 0; ii < II; ++ii)
#pragma unroll
        for (int jj = 0; jj < JJ; ++jj) acc[ii][jj] = cjp[jj];

    float4 rbuf[PF];
#pragma unroll
    for (int p = 0; p < PF; ++p)
        rbuf[p] = *reinterpret_cast<const float4*>(&Rt[p * N + j0]);

    for (int hb = 0; hb < H - PF; hb += PF) {   // hb = 0..112
#pragma unroll
        for (int p = 0; p < PF; ++p) {
            const int h = hb + p;
            const float4 r = rbuf[p];
            rbuf[p] = *reinterpret_cast<const float4*>(&Rt[(h + PF) * N + j0]);
            const float4 lv = *reinterpret_cast<const float4*>(&LsT[h][0]);
            const float s = sgn[h];
            const float* lp = &lv.x;
            const float* rp = &r.x;
#pragma unroll
            for (int ii = 0; ii < II; ++ii)
#pragma unroll
                for (int jj = 0; jj < JJ; ++jj)
                    acc[ii][jj] = fmaf(s, fabsf(lp[ii] + rp[jj]), acc[ii][jj]);
        }
    }
#pragma unroll
    for (int p = 0; p < PF; ++p) {       // tail: h = 120..127, no prefetch
        const int h = H - PF + p;
        const float4 r = rbuf[p];
        const float4 lv = *reinterpret_cast<const float4*>(&LsT[h][0]);
        const float s = sgn[h];
        const float* lp = &lv.x;
        const float* rp = &r.x;
#pragma unroll
        for (int ii = 0; ii < II; ++ii)
#pragma unroll
            for (int jj = 0; jj < JJ; ++jj)
                acc[ii][jj] = fmaf(s, fabsf(lp[ii] + rp[jj]), acc[ii][jj]);
    }

    // ---- softmax over j (block = full row) ----
#pragma unroll
    for (int ii = 0; ii < II; ++ii) {
        float m = fmaxf(fmaxf(acc[ii][0], acc[ii][1]),
                        fmaxf(acc[ii][2], acc[ii][3]));
#pragma unroll
        for (int off = 32; off; off >>= 1) m = fmaxf(m, __shfl_xor(m, off));
        if (lane == 0) red_m[ii][wave] = m;
    }
    __syncthreads();

    float mm[II];
#pragma unroll
    for (int ii = 0; ii < II; ++ii)
        mm[ii] = fmaxf(fmaxf(red_m[ii][0], red_m[ii][1]),
                       fmaxf(red_m[ii][2], red_m[ii][3]));

#pragma unroll
    for (int ii = 0; ii < II; ++ii) {
        float s = 0.f;
#pragma unroll
        for (int jj = 0; jj < JJ; ++jj) {
            acc[ii][jj] = expf(acc[ii][jj] - mm[ii]);
            s += acc[ii][jj];
        }
#pragma unroll
        for (int off = 32; off; off >>= 1) s += __shfl_xor(s, off);
        if (lane == 0) red_s[ii][wave] = s;
    }
    __syncthreads();

#pragma unroll
    for (int ii = 0; ii < II; ++ii) {
        const float s = red_s[ii][0] + red_s[ii][1] + red_s[ii][2] + red_s[ii][3];
        const float rcp = 1.0f / s;
        float4 o;
        o.x = acc[ii][0] * rcp; o.y = acc[ii][1] * rcp;
        o.z = acc[ii][2] * rcp; o.w = acc[ii][3] * rcp;
        *reinterpret_cast<float4*>(&out[(i0 + ii) * N + j0]) = o;
    }
}

extern "C" void kernel_launch(void* const* d_in, const int* in_sizes, int n_in,
                              void* d_out, int out_size, void* d_ws, size_t ws_size,
                              hipStream_t stream) {
    const float* x  = (const float*)d_in[0];   // (N,H)
    const float* W1 = (const float*)d_in[1];   // (2H,H)
    const float* b1 = (const float*)d_in[2];   // (H,)
    const float* W2 = (const float*)d_in[3];   // (H,1)
    // d_in[4] = b2 — cancels under softmax, not needed.
    float* out = (float*)d_out;

    float* Lp = (float*)d_ws;        // N*H
    float* Rt = Lp + N * H;          // H*N (transposed, w2-scaled)
    float* cc = Rt + H * N;          // N

    prep_kernel<<<N / 4, 512, 0, stream>>>(x, W1, b1, W2, Lp, Rt, cc);
    adj_kernel<<<N / 4, 256, 0, stream>>>(Lp, Rt, W2, cc, out);
}

// Round 16
// 25.425 us; speedup vs baseline: 1.4345x; 1.0540x over previous
//
#include <hip/hip_runtime.h>

#define H 128
#define N 1024

// ---------------------------------------------------------------------------
// CHAMPION (reproduced 25.50 / 25.58 us; session best).
//
// Math: logits row-softmax is invariant to row-constants, so with
//   u_h = w2[h]*(L[i][h]+b1[h]+R[j][h]) = Lp[i][h]+Rt[h][j],
//   sum_h w2*relu(.) = const_i + c_j + sum_h s_h*|u_h|, s_h = ±0.5.
// b2 and const_i cancel; c_j precomputed (pre-halved).
//
// prep: grid N/4 = 256 blocks x 512 threads (8 waves/CU).
//   waves 0-3 L2-normalize rows (shuffle reduce); quarter q = t>>7 picks
//   L/R half of W1, row pair {0,1}/{2,3}; PF=8 register-pipelined W1 loads.
//   Lp[i][h] = w2[h]*(L+b1)  (coalesced row-major stores)
//   Rt[h][j] = w2[h]*R       (transposed for adj's coalesced j-stream)
//   c[j] = 0.5*sum_h Rt[h][j] (shuffle + cred reduction)
// ---------------------------------------------------------------------------
__global__ __launch_bounds__(512) void prep_kernel(
    const float* __restrict__ x, const float* __restrict__ W1,
    const float* __restrict__ b1, const float* __restrict__ W2,
    float* __restrict__ Lp, float* __restrict__ Rt, float* __restrict__ c)
{
    constexpr int PF = 8;
    __shared__ float e_s[4][H];
    __shared__ float cred[4][2];
    const int t = threadIdx.x;
    const int i0 = blockIdx.x * 4;

    if (t < 256) {                       // normalize: wave w owns row w
        const int row = t >> 6, lane = t & 63;
        const float2 v = *reinterpret_cast<const float2*>(&x[(i0 + row) * H + 2 * lane]);
        float s = v.x * v.x + v.y * v.y;
#pragma unroll
        for (int off = 32; off; off >>= 1) s += __shfl_xor(s, off);
        const float rn = 1.0f / fmaxf(sqrtf(s), 1e-12f);
        e_s[row][2 * lane]     = v.x * rn;
        e_s[row][2 * lane + 1] = v.y * rn;
    }
    __syncthreads();

    const int h = t & (H - 1);
    const int q = t >> 7;                // 0,1 -> L ; 2,3 -> R
    const int r0 = (q & 1) * 2;          // row pair {0,1} or {2,3}
    const float* Wb = W1 + (q >= 2 ? H * H : 0) + h;

    float acc0 = 0.f, acc1 = 0.f;
    float wbuf[PF];
#pragma unroll
    for (int p = 0; p < PF; ++p) wbuf[p] = Wb[p * H];

    for (int kb = 0; kb < H - PF; kb += PF) {
#pragma unroll
        for (int p = 0; p < PF; ++p) {
            const float w = wbuf[p];
            wbuf[p] = Wb[(kb + p + PF) * H];
            acc0 = fmaf(e_s[r0][kb + p],     w, acc0);
            acc1 = fmaf(e_s[r0 + 1][kb + p], w, acc1);
        }
    }
#pragma unroll
    for (int p = 0; p < PF; ++p) {
        const int k = H - PF + p;
        acc0 = fmaf(e_s[r0][k],     wbuf[p], acc0);
        acc1 = fmaf(e_s[r0 + 1][k], wbuf[p], acc1);
    }

    const float w2h = W2[h];
    if (q < 2) {
        const float bb = b1[h];
        Lp[(i0 + r0) * H + h]     = w2h * (acc0 + bb);
        Lp[(i0 + r0 + 1) * H + h] = w2h * (acc1 + bb);
    } else {
        const float v0 = w2h * acc0, v1 = w2h * acc1;
        Rt[h * N + (i0 + r0)]     = v0;
        Rt[h * N + (i0 + r0 + 1)] = v1;
        float s0 = v0, s1 = v1;          // c_j partial sums over h
#pragma unroll
        for (int off = 32; off; off >>= 1) {
            s0 += __shfl_xor(s0, off);
            s1 += __shfl_xor(s1, off);
        }
        const int wv = t >> 6;           // 4..7
        if ((t & 63) == 0) { cred[wv - 4][0] = s0; cred[wv - 4][1] = s1; }
    }
    __syncthreads();
    if (t < 4) {                         // c[i0+r]: combine the 2 waves per row
        const int r = t;
        c[i0 + r] = 0.5f * (cred[(r >> 1) * 2][r & 1] + cred[(r >> 1) * 2 + 1][r & 1]);
    }
}

// ---------------------------------------------------------------------------
// adj: grid N/4 = 256 blocks x 512 threads (8 waves -> 2 waves/SIMD).
//   thread t: rows i0..i0+3, cols j0 = 2t, 2t+1.
//   logit'[i][j] = c[j] + sum_h s_h * |Lp[i][h] + Rt[h][j]|,  s_h = ±0.5
//   Inner loop: 2 VALU/element (v_add + v_fma with |.| input modifier),
//   PF=8 rotating float2 R-prefetch, Lp via one b128 LDS broadcast per h,
//   sgn via b32 LDS broadcast. Block-local softmax over j.
//   // Falsified single-deltas (each slower): PF=16 (+2.4us), SALU sign
//   // (+2.2), readlane A (+11), VMEM-uniform A (+4.7), JJ=4/256thr (+1.3),
//   // j-split+combine (+4.5), sign-partition variants (+4..8).
// ---------------------------------------------------------------------------
__global__ __launch_bounds__(512) void adj_kernel(
    const float* __restrict__ Lp, const float* __restrict__ Rt,
    const float* __restrict__ W2, const float* __restrict__ c,
    float* __restrict__ out)
{
    constexpr int II = 4, PF = 8;
    __shared__ float LsT[H][4];
    __shared__ float sgn[H];
    __shared__ float red_m[II][8];
    __shared__ float red_s[II][8];

    const int t = threadIdx.x;
    const int lane = t & 63, wave = t >> 6;
    const int i0 = blockIdx.x * II;
    const int j0 = t * 2;

    if (t < H) {
        sgn[t] = (W2[t] >= 0.f) ? 0.5f : -0.5f;
        float4 lv;
        lv.x = Lp[(i0 + 0) * H + t];
        lv.y = Lp[(i0 + 1) * H + t];
        lv.z = Lp[(i0 + 2) * H + t];
        lv.w = Lp[(i0 + 3) * H + t];
        *reinterpret_cast<float4*>(&LsT[t][0]) = lv;
    }
    const float2 cj = *reinterpret_cast<const float2*>(&c[j0]);
    __syncthreads();

    float accx[II], accy[II];
#pragma unroll
    for (int ii = 0; ii < II; ++ii) { accx[ii] = cj.x; accy[ii] = cj.y; }

    float2 rbuf[PF];
#pragma unroll
    for (int p = 0; p < PF; ++p)
        rbuf[p] = *reinterpret_cast<const float2*>(&Rt[p * N + j0]);

    for (int hb = 0; hb < H - PF; hb += PF) {
#pragma unroll
        for (int p = 0; p < PF; ++p) {
            const int h = hb + p;
            const float2 r = rbuf[p];
            rbuf[p] = *reinterpret_cast<const float2*>(&Rt[(h + PF) * N + j0]);
            const float4 lv = *reinterpret_cast<const float4*>(&LsT[h][0]);
            const float s = sgn[h];
            const float* lp = &lv.x;
#pragma unroll
            for (int ii = 0; ii < II; ++ii) {
                accx[ii] = fmaf(s, fabsf(lp[ii] + r.x), accx[ii]);
                accy[ii] = fmaf(s, fabsf(lp[ii] + r.y), accy[ii]);
            }
        }
    }
#pragma unroll
    for (int p = 0; p < PF; ++p) {       // tail, no prefetch
        const int h = H - PF + p;
        const float2 r = rbuf[p];
        const float4 lv = *reinterpret_cast<const float4*>(&LsT[h][0]);
        const float s = sgn[h];
        const float* lp = &lv.x;
#pragma unroll
        for (int ii = 0; ii < II; ++ii) {
            accx[ii] = fmaf(s, fabsf(lp[ii] + r.x), accx[ii]);
            accy[ii] = fmaf(s, fabsf(lp[ii] + r.y), accy[ii]);
        }
    }

    // ---- softmax over j (block = full row) ----
#pragma unroll
    for (int ii = 0; ii < II; ++ii) {
        float m = fmaxf(accx[ii], accy[ii]);
#pragma unroll
        for (int off = 32; off; off >>= 1) m = fmaxf(m, __shfl_xor(m, off));
        if (lane == 0) red_m[ii][wave] = m;
    }
    __syncthreads();

    float mm[II];
#pragma unroll
    for (int ii = 0; ii < II; ++ii) {
        float m = red_m[ii][0];
#pragma unroll
        for (int w = 1; w < 8; ++w) m = fmaxf(m, red_m[ii][w]);
        mm[ii] = m;
    }

#pragma unroll
    for (int ii = 0; ii < II; ++ii) {
        accx[ii] = expf(accx[ii] - mm[ii]);
        accy[ii] = expf(accy[ii] - mm[ii]);
        float s = accx[ii] + accy[ii];
#pragma unroll
        for (int off = 32; off; off >>= 1) s += __shfl_xor(s, off);
        if (lane == 0) red_s[ii][wave] = s;
    }
    __syncthreads();

#pragma unroll
    for (int ii = 0; ii < II; ++ii) {
        float s = red_s[ii][0];
#pragma unroll
        for (int w = 1; w < 8; ++w) s += red_s[ii][w];
        const float r = 1.0f / s;
        float2 o;
        o.x = accx[ii] * r;
        o.y = accy[ii] * r;
        *reinterpret_cast<float2*>(&out[(i0 + ii) * N + j0]) = o;
    }
}

extern "C" void kernel_launch(void* const* d_in, const int* in_sizes, int n_in,
                              void* d_out, int out_size, void* d_ws, size_t ws_size,
                              hipStream_t stream) {
    const float* x  = (const float*)d_in[0];   // (N,H)
    const float* W1 = (const float*)d_in[1];   // (2H,H)
    const float* b1 = (const float*)d_in[2];   // (H,)
    const float* W2 = (const float*)d_in[3];   // (H,1)
    // d_in[4] = b2 — cancels under softmax, not needed.
    float* out = (float*)d_out;

    float* Lp = (float*)d_ws;        // N*H
    float* Rt = Lp + N * H;          // H*N (transposed, w2-scaled)
    float* cc = Rt + H * N;          // N

    prep_kernel<<<N / 4, 512, 0, stream>>>(x, W1, b1, W2, Lp, Rt, cc);
    adj_kernel<<<N / 4, 512, 0, stream>>>(Lp, Rt, W2, cc, out);
}